// Round 3
// baseline (595.079 us; speedup 1.0000x reference)
//
#include <hip/hip_runtime.h>
#include <math.h>

#define T_TOK 4096
#define D_DIM 1024

typedef __attribute__((ext_vector_type(4))) float f32x4;
typedef __attribute__((ext_vector_type(8))) short s16x8;

__device__ __forceinline__ unsigned short f2bf(float f){
  union { float f; unsigned u; } v; v.f = f;
  unsigned r = v.u + 0x7FFFu + ((v.u >> 16) & 1u);   // RNE; inputs finite
  return (unsigned short)(r >> 16);
}

__device__ __forceinline__ void gld_lds16(const unsigned short* g, unsigned short* l){
  __builtin_amdgcn_global_load_lds(
      (const __attribute__((address_space(1))) unsigned int*)g,
      (__attribute__((address_space(3))) unsigned int*)l, 16, 0, 0);
}

// ---------------- router body: fp64 logits, argmax, w_t, aux-loss sums ----------------
__device__ __forceinline__ void router_body(
    int bid, char* smraw,
    const float* __restrict__ x, const float* __restrict__ gumbel,
    const float* __restrict__ rw, const float* __restrict__ rb,
    int* __restrict__ expert_id, float* __restrict__ wtok,
    double* __restrict__ prob_sums, int* __restrict__ counts)
{
  float (*sprob)[8] = (float(*)[8])smraw;
  int wave = threadIdx.x >> 6, lane = threadIdx.x & 63;
  int t = bid * 4 + wave;
  const float* xr = x + (size_t)t * D_DIM;
  double acc[8];
  #pragma unroll
  for (int e = 0; e < 8; e++) acc[e] = 0.0;
  #pragma unroll
  for (int i = 0; i < 16; i++){
    int d = i * 64 + lane;
    double xv = (double)xr[d];
    const float4* rwp = (const float4*)(rw + (size_t)d * 8);
    float4 r0 = rwp[0], r1 = rwp[1];
    acc[0] += xv * (double)r0.x; acc[1] += xv * (double)r0.y;
    acc[2] += xv * (double)r0.z; acc[3] += xv * (double)r0.w;
    acc[4] += xv * (double)r1.x; acc[5] += xv * (double)r1.y;
    acc[6] += xv * (double)r1.z; acc[7] += xv * (double)r1.w;
  }
  #pragma unroll
  for (int e = 0; e < 8; e++){
    #pragma unroll
    for (int off = 32; off; off >>= 1) acc[e] += __shfl_xor(acc[e], off);
  }
  double logit[8], z[8];
  #pragma unroll
  for (int e = 0; e < 8; e++){
    logit[e] = acc[e] + (double)rb[e];
    z[e] = logit[e] + (double)gumbel[(size_t)t * 8 + e];
  }
  int amax = 0;
  #pragma unroll
  for (int e = 1; e < 8; e++) if (z[e] > z[amax]) amax = e;   // first-max like jnp.argmax
  float zm = (float)z[amax];
  float se = 0.f;
  #pragma unroll
  for (int e = 0; e < 8; e++) se += expf((float)z[e] - zm);
  float y = 1.f / se;                 // y_soft at argmax
  float w = (1.0f - y) + y;           // replicate ref fp32 arithmetic
  double lm = logit[0];
  #pragma unroll
  for (int e = 1; e < 8; e++) lm = fmax(lm, logit[e]);
  float p[8]; float ps = 0.f;
  #pragma unroll
  for (int e = 0; e < 8; e++){ p[e] = expf((float)(logit[e] - lm)); ps += p[e]; }
  float inv = 1.f / ps;

  if (lane == 0){
    expert_id[t] = amax; wtok[t] = w;
    atomicAdd(&counts[amax], 1);
    #pragma unroll
    for (int e = 0; e < 8; e++) sprob[wave][e] = p[e] * inv;
  }
  __syncthreads();
  if (threadIdx.x < 8){
    double s = (double)sprob[0][threadIdx.x] + (double)sprob[1][threadIdx.x]
             + (double)sprob[2][threadIdx.x] + (double)sprob[3][threadIdx.x];
    atomicAdd(&prob_sums[threadIdx.x], s);
  }
}

// ---------------- transpose body: fp32 [K][N] tile -> bf16 [N][K] ----------------
__device__ __forceinline__ void transpose_body(
    const float* __restrict__ W, unsigned short* __restrict__ WT,
    int K, int N, int e, int kb, int nb, char* smraw)
{
  float (*tile)[65] = (float(*)[65])smraw;
  int k0 = kb * 64, n0 = nb * 64;
  const float* src = W + (size_t)e * K * N;
  int tid = threadIdx.x;
  int r = tid >> 4;              // 0..15
  int c4 = (tid & 15) * 4;       // 0..60
  #pragma unroll
  for (int j = 0; j < 4; j++){
    int k = r + j * 16;
    float4 v = *(const float4*)(src + (size_t)(k0 + k) * N + n0 + c4);
    tile[k][c4] = v.x; tile[k][c4 + 1] = v.y; tile[k][c4 + 2] = v.z; tile[k][c4 + 3] = v.w;
  }
  __syncthreads();
  unsigned short* dst = WT + (size_t)e * N * K;
  int n = tid >> 2;              // 0..63
  #pragma unroll
  for (int h = 0; h < 2; h++){
    int s = (tid & 3) + h * 4;   // 8-element k-segment 0..7
    unsigned short buf[8];
    #pragma unroll
    for (int j = 0; j < 8; j++) buf[j] = f2bf(tile[s * 8 + j][n]);
    *(s16x8*)(dst + (size_t)(n0 + n) * K + k0 + s * 8) = *(s16x8*)buf;
  }
}

// ---------------- K1: router (blocks 0..1023) + transpose w1 (blocks 1024..9215) ----------------
__global__ __launch_bounds__(256) void prep1_kernel(
    const float* __restrict__ x, const float* __restrict__ gumbel,
    const float* __restrict__ rw, const float* __restrict__ rb,
    int* __restrict__ expert_id, float* __restrict__ wtok,
    double* __restrict__ prob_sums, int* __restrict__ counts,
    const float* __restrict__ w1, unsigned short* __restrict__ w1T)
{
  __shared__ __align__(16) char smraw[64 * 65 * 4];
  if (blockIdx.x < 1024){
    router_body(blockIdx.x, smraw, x, gumbel, rw, rb, expert_id, wtok, prob_sums, counts);
  } else {
    int b = blockIdx.x - 1024;      // 8192 blocks: K=1024 (16 kb) x N=4096 (64 nb) x 8 e
    int e = b >> 10;
    int rem = b & 1023;
    int kb = rem & 15, nb = rem >> 4;
    transpose_body(w1, w1T, 1024, 4096, e, kb, nb, smraw);
  }
}

// ---------------- standalone transpose for w2 ----------------
__global__ __launch_bounds__(256) void transpose_w(
    const float* __restrict__ W, unsigned short* __restrict__ WT, int K, int N)
{
  __shared__ __align__(16) char smraw[64 * 65 * 4];
  transpose_body(W, WT, K, N, blockIdx.z, blockIdx.x, blockIdx.y, smraw);
}

// ---------------- finalize: offsets/cursors + aux loss ----------------
__global__ void finalize_kernel(const double* __restrict__ prob_sums, const int* __restrict__ counts,
                                int* __restrict__ offsets, int* __restrict__ cursor,
                                float* __restrict__ aux_out)
{
  if (threadIdx.x == 0){
    int off = 0; double aux = 0.0;
    for (int e = 0; e < 8; e++){ offsets[e] = off; cursor[e] = off; off += counts[e]; }
    for (int e = 0; e < 8; e++){
      double imp = prob_sums[e] / 4096.0;
      double d = imp - 0.125;
      aux += d * d;
    }
    aux_out[0] = (float)(aux / 8.0);
  }
}

// ---------------- scatter: counting-sort tokens + x -> bf16 grouped ----------------
__global__ __launch_bounds__(256) void scatter_kernel(
    const float* __restrict__ x, const int* __restrict__ expert_id, const float* __restrict__ wtok,
    int* __restrict__ cursor, int* __restrict__ token_of, float* __restrict__ gw,
    unsigned short* __restrict__ Xg)
{
  int t = blockIdx.x;
  __shared__ int spos;
  if (threadIdx.x == 0){
    int e = expert_id[t];
    int p = atomicAdd(&cursor[e], 1);
    spos = p;
    token_of[p] = t; gw[p] = wtok[t];
  }
  __syncthreads();
  int pos = spos;
  float4 v = ((const float4*)(x + (size_t)t * D_DIM))[threadIdx.x];
  ushort4 o; o.x = f2bf(v.x); o.y = f2bf(v.y); o.z = f2bf(v.z); o.w = f2bf(v.w);
  ((ushort4*)(Xg + (size_t)pos * D_DIM))[threadIdx.x] = o;
}

// ---------------- ffn1 (m97 structure): hidden = gelu(Xg @ w1T^T + b1) ----------------
// 128x128 tile, BK=32, 256 threads (2x2 waves of 64x64), mfma 16x16x32 bf16.
__global__ __launch_bounds__(256) void ffn1_kernel(
    const unsigned short* __restrict__ A,      // Xg [T][1024]
    const unsigned short* __restrict__ BT,     // w1T [E][4096][1024]
    const float* __restrict__ bias,            // b1 [E][4096]
    const int* __restrict__ counts, const int* __restrict__ offsets,
    unsigned short* __restrict__ Hout)
{
  const int K = 1024, N = 4096;
  int e = blockIdx.z;
  int cnt = counts[e];
  int by = blockIdx.y;
  if (by * 128 >= cnt) return;            // uniform early-exit
  int offs = offsets[e];
  int bx = blockIdx.x;
  int tid = threadIdx.x;
  int lane = tid & 63;
  int wv = __builtin_amdgcn_readfirstlane(tid >> 6);
  int wm = wv & 1, wn = wv >> 1;

  __shared__ unsigned short sA[128 * 32];   // 8 KB, NO padding (global_load_lds layout)
  __shared__ unsigned short sB[128 * 32];

  size_t aoff[2], boff[2];
  unsigned short *aldst[2], *bldst[2];
  #pragma unroll
  for (int j = 0; j < 2; j++){
    int c = 2 * wv + j;
    int row = c * 16 + (lane >> 2);
    int pos = offs + by * 128 + row;
    if (pos > T_TOK - 1) pos = T_TOK - 1;          // clamp; masked at store
    aoff[j] = (size_t)pos * K + (lane & 3) * 8;
    aldst[j] = &sA[c * 512];
    int n = bx * 128 + row;
    boff[j] = ((size_t)e * N + n) * K + (lane & 3) * 8;
    bldst[j] = &sB[c * 512];
  }

  f32x4 accv[4][4];
  #pragma unroll
  for (int mi = 0; mi < 4; mi++)
    #pragma unroll
    for (int ni = 0; ni < 4; ni++) accv[mi][ni] = (f32x4){0.f, 0.f, 0.f, 0.f};

  int col = lane & 15, quad = lane >> 4;
  const int NK = K / 32;
  for (int kt = 0; kt < NK; ++kt){
    __syncthreads();
    #pragma unroll
    for (int j = 0; j < 2; j++) gld_lds16(A + aoff[j] + kt * 32, aldst[j]);
    #pragma unroll
    for (int j = 0; j < 2; j++) gld_lds16(BT + boff[j] + kt * 32, bldst[j]);
    __syncthreads();
    s16x8 af[4], bf[4];
    #pragma unroll
    for (int mi = 0; mi < 4; mi++)
      af[mi] = *(const s16x8*)&sA[(wm * 64 + mi * 16 + col) * 32 + quad * 8];
    #pragma unroll
    for (int ni = 0; ni < 4; ni++)
      bf[ni] = *(const s16x8*)&sB[(wn * 64 + ni * 16 + col) * 32 + quad * 8];
    #pragma unroll
    for (int mi = 0; mi < 4; mi++)
      #pragma unroll
      for (int ni = 0; ni < 4; ni++)
        accv[mi][ni] = __builtin_amdgcn_mfma_f32_16x16x32_bf16(af[mi], bf[ni], accv[mi][ni], 0, 0, 0);
  }

  float bv[4];
  #pragma unroll
  for (int ni = 0; ni < 4; ni++)
    bv[ni] = bias[(size_t)e * N + bx * 128 + wn * 64 + ni * 16 + col];

  #pragma unroll
  for (int mi = 0; mi < 4; mi++){
    int rbase = by * 128 + wm * 64 + mi * 16 + quad * 4;
    #pragma unroll
    for (int r = 0; r < 4; r++){
      int row = rbase + r;
      if (row < cnt){
        size_t orow = (size_t)(offs + row) * N + bx * 128 + wn * 64 + col;
        #pragma unroll
        for (int ni = 0; ni < 4; ni++){
          float v = accv[mi][ni][r] + bv[ni];
          float g = 0.5f * v * (1.0f + erff(v * 0.70710678118654752f));  // exact gelu
          Hout[orow + ni * 16] = f2bf(g);
        }
      }
    }
  }
}

// ---------------- ffn2: out[tok] += w_t * (hidden @ w2T^T [+ b2]) ----------------
// split-K=2 (2048 each) + double-buffered LDS: stage(kt+1) issued before compute(kt),
// so the barrier's vmcnt(0) drain overlaps MFMA. 512 blocks = 2/CU. atomicAdd epilogue.
__global__ __launch_bounds__(256) void ffn2_kernel(
    const unsigned short* __restrict__ A,      // hidden [T][4096]
    const unsigned short* __restrict__ BT,     // w2T [E][1024][4096]
    const float* __restrict__ bias,            // b2 [E][1024]
    const int* __restrict__ counts, const int* __restrict__ offsets,
    const int* __restrict__ token_of, const float* __restrict__ gw,
    float* __restrict__ Fout)
{
  const int K = 4096, N = 1024, KL = 2048;
  int e = blockIdx.z;
  int cnt = counts[e];
  int by = blockIdx.y;
  if (by * 128 >= cnt) return;
  int offs = offsets[e];
  int bx = blockIdx.x & 7, ks = blockIdx.x >> 3;
  int tid = threadIdx.x;
  int lane = tid & 63;
  int wv = __builtin_amdgcn_readfirstlane(tid >> 6);
  int wm = wv & 1, wn = wv >> 1;

  __shared__ unsigned short sA[2][128 * 32];   // 16 KB
  __shared__ unsigned short sB[2][128 * 32];   // 16 KB

  size_t aoff[2], boff[2];
  int ach[2];
  #pragma unroll
  for (int j = 0; j < 2; j++){
    int c = 2 * wv + j;
    int row = c * 16 + (lane >> 2);
    int pos = offs + by * 128 + row;
    if (pos > T_TOK - 1) pos = T_TOK - 1;
    aoff[j] = (size_t)pos * K + (size_t)ks * KL + (lane & 3) * 8;
    int n = bx * 128 + row;
    boff[j] = ((size_t)e * N + n) * K + (size_t)ks * KL + (lane & 3) * 8;
    ach[j] = c * 512;
  }

  auto stage = [&](int kt, int b){
    #pragma unroll
    for (int j = 0; j < 2; j++) gld_lds16(A + aoff[j] + kt * 32, &sA[b][ach[j]]);
    #pragma unroll
    for (int j = 0; j < 2; j++) gld_lds16(BT + boff[j] + kt * 32, &sB[b][ach[j]]);
  };

  f32x4 accv[4][4];
  #pragma unroll
  for (int mi = 0; mi < 4; mi++)
    #pragma unroll
    for (int ni = 0; ni < 4; ni++) accv[mi][ni] = (f32x4){0.f, 0.f, 0.f, 0.f};

  stage(0, 0);
  int col = lane & 15, quad = lane >> 4;
  const int NK = KL / 32;   // 64
  for (int kt = 0; kt < NK; ++kt){
    __syncthreads();                          // drains vmcnt(0): buf[kt&1] ready
    if (kt + 1 < NK) stage(kt + 1, (kt + 1) & 1);   // in flight during compute
    int b = kt & 1;
    s16x8 af[4], bf[4];
    #pragma unroll
    for (int mi = 0; mi < 4; mi++)
      af[mi] = *(const s16x8*)&sA[b][(wm * 64 + mi * 16 + col) * 32 + quad * 8];
    #pragma unroll
    for (int ni = 0; ni < 4; ni++)
      bf[ni] = *(const s16x8*)&sB[b][(wn * 64 + ni * 16 + col) * 32 + quad * 8];
    #pragma unroll
    for (int mi = 0; mi < 4; mi++)
      #pragma unroll
      for (int ni = 0; ni < 4; ni++)
        accv[mi][ni] = __builtin_amdgcn_mfma_f32_16x16x32_bf16(af[mi], bf[ni], accv[mi][ni], 0, 0, 0);
  }

  float bv[4];
  #pragma unroll
  for (int ni = 0; ni < 4; ni++)
    bv[ni] = bias[(size_t)e * N + bx * 128 + wn * 64 + ni * 16 + col];

  #pragma unroll
  for (int mi = 0; mi < 4; mi++){
    int rbase = by * 128 + wm * 64 + mi * 16 + quad * 4;
    #pragma unroll
    for (int r = 0; r < 4; r++){
      int row = rbase + r;
      if (row < cnt){
        int pos = offs + row;
        int tok = token_of[pos];
        float wgt = gw[pos];
        size_t orow = (size_t)tok * N + bx * 128 + wn * 64 + col;
        #pragma unroll
        for (int ni = 0; ni < 4; ni++){
          float v = accv[mi][ni][r];
          if (ks == 0) v += bv[ni];
          atomicAdd(&Fout[orow + ni * 16], v * wgt);
        }
      }
    }
  }
}

extern "C" void kernel_launch(void* const* d_in, const int* in_sizes, int n_in,
                              void* d_out, int out_size, void* d_ws, size_t ws_size,
                              hipStream_t stream)
{
  const float* x      = (const float*)d_in[0];
  const float* gumbel = (const float*)d_in[1];
  const float* rw     = (const float*)d_in[2];
  const float* rb     = (const float*)d_in[3];
  const float* w1     = (const float*)d_in[4];
  const float* b1     = (const float*)d_in[5];
  const float* w2     = (const float*)d_in[6];
  const float* b2     = (const float*)d_in[7];
  float* out = (float*)d_out;

  char* ws = (char*)d_ws;
  double* prob_sums = (double*)(ws + 0);     // 64 B
  int* counts    = (int*)(ws + 64);
  int* offsets   = (int*)(ws + 96);
  int* cursor    = (int*)(ws + 128);
  int* expert_id = (int*)(ws + 256);                    // 16 KB
  float* wtok    = (float*)(ws + 256 + 16384);          // 16 KB
  int* token_of  = (int*)(ws + 256 + 2 * 16384);        // 16 KB
  float* gw      = (float*)(ws + 256 + 3 * 16384);      // 16 KB -> ends at 65792
  unsigned short* Xg     = (unsigned short*)(ws + 65792);             // 8 MiB bf16
  unsigned short* hidden = (unsigned short*)(ws + 65792 + 8388608);   // 32 MiB bf16
  unsigned short* wT     = (unsigned short*)(ws + 65792 + 8388608 + 33554432); // 64 MiB shared w1T/w2T

  hipMemsetAsync(ws, 0, 256, stream);                              // atomic accumulators
  hipMemsetAsync(out, 0, (size_t)out_size * sizeof(float), stream); // ffn2 atomicAdd target

  // K1: router (1024 blocks) + w1 transpose (8192 blocks)
  prep1_kernel<<<9216, 256, 0, stream>>>(x, gumbel, rw, rb, expert_id, wtok,
                                         prob_sums, counts, w1, wT);
  finalize_kernel<<<1, 64, 0, stream>>>(prob_sums, counts, offsets, cursor, out + 4194304);
  scatter_kernel<<<4096, 256, 0, stream>>>(x, expert_id, wtok, cursor, token_of, gw, Xg);

  // hidden = gelu(Xg @ w1[e] + b1[e])   (M=cnt_e, N=4096, K=1024)
  ffn1_kernel<<<dim3(32, 32, 8), 256, 0, stream>>>(Xg, wT, b1, counts, offsets, hidden);

  // w2T = bf16 transpose of w2 (reuses wT slab, stream-ordered after ffn1)
  transpose_w<<<dim3(64, 16, 8), 256, 0, stream>>>(w2, wT, 4096, 1024);

  // out[tok] = w_t * (hidden @ w2[e] + b2[e]), split-K=2 with atomic combine
  ffn2_kernel<<<dim3(16, 32, 8), 256, 0, stream>>>(hidden, wT, b2, counts, offsets,
                                                   token_of, gw, out);
}